// Round 2
// baseline (263.376 us; speedup 1.0000x reference)
//
#include <hip/hip_runtime.h>
#include <math.h>

typedef __attribute__((ext_vector_type(8))) short short8;
typedef __attribute__((ext_vector_type(4))) float floatx4;

__device__ __forceinline__ float bf2f(unsigned short u) {
    union { unsigned int u; float f; } v;
    v.u = ((unsigned int)u) << 16;
    return v.f;
}

__device__ __forceinline__ unsigned short f2bf(float f) {
    union { float f; unsigned int u; } v;
    v.f = f;
    unsigned int r = v.u + 0x7fffu + ((v.u >> 16) & 1u);  // RNE
    return (unsigned short)(r >> 16);
}

__device__ __forceinline__ void gload16_lds(const void* g, void* l) {
    __builtin_amdgcn_global_load_lds(
        (const __attribute__((address_space(1))) unsigned int*)g,
        (__attribute__((address_space(3))) unsigned int*)l, 16, 0, 0);
}

// ---- xb[m] = bf16( x[m] / max(||x_m||,1e-12) )  (fp32 in, bf16 out, D=1024) ---
__global__ __launch_bounds__(256) void xfold_kernel(const float* __restrict__ x,
                                                    unsigned short* __restrict__ xb, int D) {
    const int row = blockIdx.x;
    const int t = threadIdx.x;
    float4 v = ((const float4*)(x + (size_t)row * D))[t];  // D == 1024 = 256*4
    float s = v.x * v.x + v.y * v.y + v.z * v.z + v.w * v.w;
#pragma unroll
    for (int o = 32; o > 0; o >>= 1) s += __shfl_xor(s, o, 64);
    __shared__ float ls[4];
    __shared__ float facs;
    if ((t & 63) == 0) ls[t >> 6] = s;
    __syncthreads();
    if (t == 0) {
        float tot = ls[0] + ls[1] + ls[2] + ls[3];
        facs = 1.0f / fmaxf(sqrtf(tot), 1e-12f);
    }
    __syncthreads();
    const float fa = facs;
    ushort4 o4;
    o4.x = f2bf(v.x * fa); o4.y = f2bf(v.y * fa);
    o4.z = f2bf(v.z * fa); o4.w = f2bf(v.w * fa);
    ((ushort4*)(xb + (size_t)row * D))[t] = o4;
}

// --- kf[t] = bf16( key[t] * sigmoid(temp[t]) / max(||key_t||,1e-12) ) (fp32 in) -
__global__ __launch_bounds__(256) void kfold_kernel(const float* __restrict__ key,
                                                    const float* __restrict__ temp,
                                                    unsigned short* __restrict__ kf, int D) {
    const int trow = blockIdx.x;
    const int t = threadIdx.x;
    float4 v = ((const float4*)(key + (size_t)trow * D))[t];
    float s = v.x * v.x + v.y * v.y + v.z * v.z + v.w * v.w;
#pragma unroll
    for (int o = 32; o > 0; o >>= 1) s += __shfl_xor(s, o, 64);
    __shared__ float ls[4];
    __shared__ float facs;
    if ((t & 63) == 0) ls[t >> 6] = s;
    __syncthreads();
    if (t == 0) {
        float tot = ls[0] + ls[1] + ls[2] + ls[3];
        float tf = temp[trow];
        float sig = 1.0f / (1.0f + expf(-tf));
        facs = sig / fmaxf(sqrtf(tot), 1e-12f);
    }
    __syncthreads();
    const float fa = facs;
    ushort4 o4;
    o4.x = f2bf(v.x * fa); o4.y = f2bf(v.y * fa);
    o4.z = f2bf(v.z * fa); o4.w = f2bf(v.w * fa);
    ((ushort4*)(kf + (size_t)trow * D))[t] = o4;
}

// ------ 64x64 tiled transpose+convert: VT[c][r] = bf16(V[r][c]), V fp32 --------
__global__ __launch_bounds__(256) void transpose_kernel(const float* __restrict__ V,
                                                        unsigned short* __restrict__ VT,
                                                        int R, int Ccols) {
    __shared__ unsigned short tile[64][65];
    const int r0 = blockIdx.y * 64;
    const int c0 = blockIdx.x * 64;
    for (int i = threadIdx.x; i < 4096; i += 256) {
        int r = i >> 6, c = i & 63;
        tile[r][c] = f2bf(V[(size_t)(r0 + r) * Ccols + c0 + c]);
    }
    __syncthreads();
    for (int i = threadIdx.x; i < 4096; i += 256) {
        int r = i >> 6, c = i & 63;
        VT[(size_t)(c0 + r) * R + r0 + c] = tile[c][r];
    }
}

// ------- 128x128 bf16 MFMA GEMM, C[M,N] = A[M,K] * B[N,K]^T (m97 structure) ----
// MODE 0: C(bf16) = acc; rowsq[m] += sum(acc^2)   (GEMM1: sim)
// MODE 1: C(fp32) = acc                           (GEMM2: out)
template <int MODE>
__global__ __launch_bounds__(256) void gemm_bt(const unsigned short* __restrict__ A,
                                               const unsigned short* __restrict__ B,
                                               void* __restrict__ Cv,
                                               float* __restrict__ rowsq,
                                               int M, int N, int K) {
    __shared__ __align__(16) unsigned short As[128 * 32];
    __shared__ __align__(16) unsigned short Bs[128 * 32];
    const int tid = threadIdx.x;
    const int lane = tid & 63;
    const int w = tid >> 6;
    const int m0 = blockIdx.y * 128;
    const int n0 = blockIdx.x * 128;
    const int wm = (w & 1) * 64;
    const int wn = (w >> 1) * 64;
    const int cl = lane & 15;
    const int q = lane >> 4;

    floatx4 acc[4][4];
#pragma unroll
    for (int i = 0; i < 4; i++)
#pragma unroll
        for (int j = 0; j < 4; j++) acc[i][j] = (floatx4){0.f, 0.f, 0.f, 0.f};

    // staging: lane-sequential LDS (global_load_lds is wave-uniform base + lane*16B)
    const int srow = tid >> 2;          // w*16 + lane>>2
    const int skof = (tid & 3) * 8;
    const unsigned short* ga0 = A + (size_t)(m0 + srow) * K + skof;
    const unsigned short* ga1 = A + (size_t)(m0 + srow + 64) * K + skof;
    const unsigned short* gb0 = B + (size_t)(n0 + srow) * K + skof;
    const unsigned short* gb1 = B + (size_t)(n0 + srow + 64) * K + skof;
    unsigned short* la0 = &As[(w * 64) * 8];
    unsigned short* la1 = &As[(256 + w * 64) * 8];
    unsigned short* lb0 = &Bs[(w * 64) * 8];
    unsigned short* lb1 = &Bs[(256 + w * 64) * 8];

    // fragment offsets: A[m=lane&15][k=q*8+j], LDS row stride 32 elems
    const int a_off = (wm + cl) * 32 + q * 8;
    const int b_off = (wn + cl) * 32 + q * 8;

    for (int kt = 0; kt < K; kt += 32) {
        __syncthreads();
        gload16_lds(ga0 + kt, la0);
        gload16_lds(ga1 + kt, la1);
        gload16_lds(gb0 + kt, lb0);
        gload16_lds(gb1 + kt, lb1);
        __syncthreads();
        short8 af[4], bfr[4];
#pragma unroll
        for (int mt = 0; mt < 4; mt++) af[mt] = *(const short8*)&As[a_off + mt * 16 * 32];
#pragma unroll
        for (int nt = 0; nt < 4; nt++) bfr[nt] = *(const short8*)&Bs[b_off + nt * 16 * 32];
#pragma unroll
        for (int mt = 0; mt < 4; mt++)
#pragma unroll
            for (int nt = 0; nt < 4; nt++)
                acc[mt][nt] = __builtin_amdgcn_mfma_f32_16x16x32_bf16(af[mt], bfr[nt],
                                                                      acc[mt][nt], 0, 0, 0);
    }

    // epilogue — C/D layout: col = lane&15, row = q*4 + reg
#pragma unroll
    for (int mt = 0; mt < 4; mt++) {
#pragma unroll
        for (int r = 0; r < 4; r++) {
            const int m = m0 + wm + mt * 16 + q * 4 + r;
            if (MODE == 0) {
                unsigned short* C = (unsigned short*)Cv;
                float ssq = 0.f;
#pragma unroll
                for (int nt = 0; nt < 4; nt++) {
                    float v = acc[mt][nt][r];
                    ssq += v * v;
                    C[(size_t)m * N + n0 + wn + nt * 16 + cl] = f2bf(v);
                }
#pragma unroll
                for (int o = 1; o < 16; o <<= 1) ssq += __shfl_xor(ssq, o, 64);
                if (cl == 0) atomicAdd(&rowsq[m], ssq);
            } else {
                float* C = (float*)Cv;
#pragma unroll
                for (int nt = 0; nt < 4; nt++)
                    C[(size_t)m * N + n0 + wn + nt * 16 + cl] = acc[mt][nt][r];
            }
        }
    }
}

// ---------- in-place: sim = bf16(gelu_exact(sim * sqrt(T)/sqrt(rowsq[row]))) ---
__global__ __launch_bounds__(256) void gelu_kernel(unsigned short* __restrict__ sim,
                                                   const float* __restrict__ rowsq,
                                                   int T, float sqrtT) {
    const int row = blockIdx.x;
    const float scale = sqrtT / fmaxf(sqrtf(rowsq[row]), 1e-30f);
    ushort4* p = (ushort4*)(sim + (size_t)row * T);
    ushort4 v = p[threadIdx.x];
    float z0 = bf2f(v.x) * scale;
    float z1 = bf2f(v.y) * scale;
    float z2 = bf2f(v.z) * scale;
    float z3 = bf2f(v.w) * scale;
    const float k = 0.70710678118654752f;
    v.x = f2bf(0.5f * z0 * (1.0f + erff(z0 * k)));
    v.y = f2bf(0.5f * z1 * (1.0f + erff(z1 * k)));
    v.z = f2bf(0.5f * z2 * (1.0f + erff(z2 * k)));
    v.w = f2bf(0.5f * z3 * (1.0f + erff(z3 * k)));
    p[threadIdx.x] = v;
}

extern "C" void kernel_launch(void* const* d_in, const int* in_sizes, int n_in,
                              void* d_out, int out_size, void* d_ws, size_t ws_size,
                              hipStream_t stream) {
    const float* x    = (const float*)d_in[0];  // [M, D] fp32
    const float* key  = (const float*)d_in[1];  // [T, D] fp32
    const float* val  = (const float*)d_in[2];  // [T, Dout] fp32
    const float* temp = (const float*)d_in[3];  // [T] fp32
    float* out = (float*)d_out;                 // [M, Dout] fp32

    const int T = in_sizes[3];              // 1024
    const int D = in_sizes[1] / T;          // 1024
    const int Dout = in_sizes[2] / T;       // 1024
    const int M = in_sizes[0] / D;          // 16384

    char* ws = (char*)d_ws;
    size_t off = 0;
    unsigned short* xb  = (unsigned short*)(ws + off); off += (size_t)M * D * 2;      // 33.5 MB
    unsigned short* sim = (unsigned short*)(ws + off); off += (size_t)M * T * 2;      // 33.5 MB
    unsigned short* kf  = (unsigned short*)(ws + off); off += (size_t)T * D * 2;      // 2 MB
    unsigned short* VT  = (unsigned short*)(ws + off); off += (size_t)Dout * T * 2;   // 2 MB
    float* rowsq = (float*)(ws + off); off += (size_t)M * 4;
    (void)ws_size; (void)n_in; (void)out_size;

    hipMemsetAsync(rowsq, 0, (size_t)M * sizeof(float), stream);
    xfold_kernel<<<M, 256, 0, stream>>>(x, xb, D);
    kfold_kernel<<<T, 256, 0, stream>>>(key, temp, kf, D);
    transpose_kernel<<<dim3(Dout / 64, T / 64), 256, 0, stream>>>(val, VT, T, Dout);
    gemm_bt<0><<<dim3(T / 128, M / 128), 256, 0, stream>>>(xb, kf, sim, rowsq, M, T, D);
    gelu_kernel<<<M, 256, 0, stream>>>(sim, rowsq, T, sqrtf((float)T));
    gemm_bt<1><<<dim3(Dout / 128, M / 128), 256, 0, stream>>>(sim, VT, out, nullptr,
                                                              M, Dout, T);
}

// Round 3
// 243.124 us; speedup vs baseline: 1.0833x; 1.0833x over previous
//
#include <hip/hip_runtime.h>
#include <math.h>

typedef __attribute__((ext_vector_type(8))) short short8;
typedef __attribute__((ext_vector_type(4))) float floatx4;

__device__ __forceinline__ float bf2f(unsigned short u) {
    union { unsigned int u; float f; } v;
    v.u = ((unsigned int)u) << 16;
    return v.f;
}

__device__ __forceinline__ unsigned short f2bf(float f) {
    union { float f; unsigned int u; } v;
    v.f = f;
    unsigned int r = v.u + 0x7fffu + ((v.u >> 16) & 1u);  // RNE
    return (unsigned short)(r >> 16);
}

__device__ __forceinline__ void gload16_lds(const void* g, void* l) {
    __builtin_amdgcn_global_load_lds(
        (const __attribute__((address_space(1))) unsigned int*)g,
        (__attribute__((address_space(3))) unsigned int*)l, 16, 0, 0);
}

// ---------------- fused prep: xfold | kfold | transpose(value) -----------------
// blocks [0, M):        xb[m] = bf16(x[m]/max(||x_m||,eps));  rowsq[m] = 0
// blocks [M, M+T):      kf[t] = bf16(key[t]*sigmoid(temp[t])/max(||key_t||,eps))
// blocks [M+T, ...):    64x64 tile transpose VT[c][r] = bf16(val[r][c])
__global__ __launch_bounds__(256) void prep_kernel(
    const float* __restrict__ x, const float* __restrict__ key,
    const float* __restrict__ temp, const float* __restrict__ val,
    unsigned short* __restrict__ xb, unsigned short* __restrict__ kf,
    unsigned short* __restrict__ VT, float* __restrict__ rowsq,
    int M, int T, int D, int Dout) {
    const int bid = blockIdx.x;
    const int t = threadIdx.x;
    __shared__ float ls[4];
    __shared__ float facs;
    __shared__ unsigned short tile[64][65];

    if (bid < M + T) {
        const bool isx = bid < M;
        const int row = isx ? bid : bid - M;
        const float* src = isx ? (x + (size_t)row * D) : (key + (size_t)row * D);
        float4 v = ((const float4*)src)[t];  // D == 1024 = 256*4
        float s = v.x * v.x + v.y * v.y + v.z * v.z + v.w * v.w;
#pragma unroll
        for (int o = 32; o > 0; o >>= 1) s += __shfl_xor(s, o, 64);
        if ((t & 63) == 0) ls[t >> 6] = s;
        __syncthreads();
        if (t == 0) {
            float tot = ls[0] + ls[1] + ls[2] + ls[3];
            float inv = 1.0f / fmaxf(sqrtf(tot), 1e-12f);
            if (isx) {
                facs = inv;
                rowsq[row] = 0.0f;
            } else {
                float tf = temp[row];
                facs = inv / (1.0f + expf(-tf));
            }
        }
        __syncthreads();
        const float fa = facs;
        ushort4 o4;
        o4.x = f2bf(v.x * fa); o4.y = f2bf(v.y * fa);
        o4.z = f2bf(v.z * fa); o4.w = f2bf(v.w * fa);
        unsigned short* dst = isx ? (xb + (size_t)row * D) : (kf + (size_t)row * D);
        ((ushort4*)dst)[t] = o4;
    } else {
        const int idx = bid - M - T;
        const int nCt = Dout >> 6;
        const int c0 = (idx % nCt) * 64;
        const int r0 = (idx / nCt) * 64;
        for (int i = t; i < 4096; i += 256) {
            int r = i >> 6, c = i & 63;
            tile[r][c] = f2bf(val[(size_t)(r0 + r) * Dout + c0 + c]);
        }
        __syncthreads();
        for (int i = t; i < 4096; i += 256) {
            int r = i >> 6, c = i & 63;
            VT[(size_t)(c0 + r) * T + r0 + c] = tile[c][r];
        }
    }
}

// ------- 128x128 bf16 MFMA GEMM, C[M,N] = A[M,K] * B[N,K]^T, BK=64 -------------
// grid = (M/128, N/128): linear id = mx + (M/128)*ny -> XCD = mx % 8, so each
// XCD owns M-stripes == k (mod 8); A stripe stays L2-resident across its 8
// N-tile blocks. LDS: two m97-format 32-k subtiles per operand (identity
// staging layout per subtile keeps global_load_lds lane-sequential).
// MODE 0: C(bf16) = acc; rowsq[m] += sum(acc^2)   (GEMM1: sim)
// MODE 1: C(fp32) = acc                           (GEMM2: out)
template <int MODE>
__global__ __launch_bounds__(256) void gemm_bt(const unsigned short* __restrict__ A,
                                               const unsigned short* __restrict__ B,
                                               void* __restrict__ Cv,
                                               float* __restrict__ rowsq,
                                               int M, int N, int K) {
    __shared__ __align__(16) unsigned short As[128 * 64];  // 16 KB: subtile0 | subtile1
    __shared__ __align__(16) unsigned short Bs[128 * 64];
    const int tid = threadIdx.x;
    const int lane = tid & 63;
    const int w = tid >> 6;
    const int m0 = blockIdx.x * 128;   // M on x (fast dim) -> XCD = m-tile % 8
    const int n0 = blockIdx.y * 128;
    const int wm = (w & 1) * 64;
    const int wn = (w >> 1) * 64;
    const int cl = lane & 15;
    const int q = lane >> 4;

    floatx4 acc[4][4];
#pragma unroll
    for (int i = 0; i < 4; i++)
#pragma unroll
        for (int j = 0; j < 4; j++) acc[i][j] = (floatx4){0.f, 0.f, 0.f, 0.f};

    // staging (per 32-k subtile, m97 layout): thread t covers row t>>2,
    // k-offset (t&3)*8; LDS elem offset = chunk*8, lane-sequential per wave
    const int srow = tid >> 2;
    const int skof = (tid & 3) * 8;
    const unsigned short* ga0 = A + (size_t)(m0 + srow) * K + skof;
    const unsigned short* ga1 = A + (size_t)(m0 + srow + 64) * K + skof;
    const unsigned short* gb0 = B + (size_t)(n0 + srow) * K + skof;
    const unsigned short* gb1 = B + (size_t)(n0 + srow + 64) * K + skof;
    unsigned short* la0 = &As[(w * 64) * 8];
    unsigned short* la1 = &As[(256 + w * 64) * 8];
    unsigned short* lb0 = &Bs[(w * 64) * 8];
    unsigned short* lb1 = &Bs[(256 + w * 64) * 8];

    // fragment offsets within a subtile: A[m=lane&15][k=q*8+j], row stride 32
    const int a_off = (wm + cl) * 32 + q * 8;
    const int b_off = (wn + cl) * 32 + q * 8;

    for (int kt = 0; kt < K; kt += 64) {
        __syncthreads();
#pragma unroll
        for (int h = 0; h < 2; h++) {
            const int go = kt + h * 32;
            const int lo = h * 4096;  // elems: 8 KB per subtile
            gload16_lds(ga0 + go, la0 + lo);
            gload16_lds(ga1 + go, la1 + lo);
            gload16_lds(gb0 + go, lb0 + lo);
            gload16_lds(gb1 + go, lb1 + lo);
        }
        __syncthreads();
#pragma unroll
        for (int h = 0; h < 2; h++) {
            const int lo = h * 4096;
            short8 af[4], bfr[4];
#pragma unroll
            for (int mt = 0; mt < 4; mt++)
                af[mt] = *(const short8*)&As[lo + a_off + mt * 16 * 32];
#pragma unroll
            for (int nt = 0; nt < 4; nt++)
                bfr[nt] = *(const short8*)&Bs[lo + b_off + nt * 16 * 32];
#pragma unroll
            for (int mt = 0; mt < 4; mt++)
#pragma unroll
                for (int nt = 0; nt < 4; nt++)
                    acc[mt][nt] = __builtin_amdgcn_mfma_f32_16x16x32_bf16(
                        af[mt], bfr[nt], acc[mt][nt], 0, 0, 0);
        }
    }

    // epilogue — C/D layout: col = lane&15, row = q*4 + reg
#pragma unroll
    for (int mt = 0; mt < 4; mt++) {
#pragma unroll
        for (int r = 0; r < 4; r++) {
            const int m = m0 + wm + mt * 16 + q * 4 + r;
            if (MODE == 0) {
                unsigned short* C = (unsigned short*)Cv;
                float ssq = 0.f;
#pragma unroll
                for (int nt = 0; nt < 4; nt++) {
                    float v = acc[mt][nt][r];
                    ssq += v * v;
                    C[(size_t)m * N + n0 + wn + nt * 16 + cl] = f2bf(v);
                }
#pragma unroll
                for (int o = 1; o < 16; o <<= 1) ssq += __shfl_xor(ssq, o, 64);
                if (cl == 0) atomicAdd(&rowsq[m], ssq);
            } else {
                float* C = (float*)Cv;
#pragma unroll
                for (int nt = 0; nt < 4; nt++)
                    C[(size_t)m * N + n0 + wn + nt * 16 + cl] = acc[mt][nt][r];
            }
        }
    }
}

// ---------- in-place: sim = bf16(gelu_exact(sim * sqrt(T)/sqrt(rowsq[row]))) ---
__global__ __launch_bounds__(256) void gelu_kernel(unsigned short* __restrict__ sim,
                                                   const float* __restrict__ rowsq,
                                                   int T, float sqrtT) {
    const int row = blockIdx.x;
    const float scale = sqrtT / fmaxf(sqrtf(rowsq[row]), 1e-30f);
    ushort4* p = (ushort4*)(sim + (size_t)row * T);
    ushort4 v = p[threadIdx.x];
    float z0 = bf2f(v.x) * scale;
    float z1 = bf2f(v.y) * scale;
    float z2 = bf2f(v.z) * scale;
    float z3 = bf2f(v.w) * scale;
    const float k = 0.70710678118654752f;
    v.x = f2bf(0.5f * z0 * (1.0f + erff(z0 * k)));
    v.y = f2bf(0.5f * z1 * (1.0f + erff(z1 * k)));
    v.z = f2bf(0.5f * z2 * (1.0f + erff(z2 * k)));
    v.w = f2bf(0.5f * z3 * (1.0f + erff(z3 * k)));
    p[threadIdx.x] = v;
}

extern "C" void kernel_launch(void* const* d_in, const int* in_sizes, int n_in,
                              void* d_out, int out_size, void* d_ws, size_t ws_size,
                              hipStream_t stream) {
    const float* x    = (const float*)d_in[0];  // [M, D] fp32
    const float* key  = (const float*)d_in[1];  // [T, D] fp32
    const float* val  = (const float*)d_in[2];  // [T, Dout] fp32
    const float* temp = (const float*)d_in[3];  // [T] fp32
    float* out = (float*)d_out;                 // [M, Dout] fp32

    const int T = in_sizes[3];              // 1024
    const int D = in_sizes[1] / T;          // 1024
    const int Dout = in_sizes[2] / T;       // 1024
    const int M = in_sizes[0] / D;          // 16384

    char* ws = (char*)d_ws;
    size_t off = 0;
    unsigned short* xb  = (unsigned short*)(ws + off); off += (size_t)M * D * 2;
    unsigned short* sim = (unsigned short*)(ws + off); off += (size_t)M * T * 2;
    unsigned short* kf  = (unsigned short*)(ws + off); off += (size_t)T * D * 2;
    unsigned short* VT  = (unsigned short*)(ws + off); off += (size_t)Dout * T * 2;
    float* rowsq = (float*)(ws + off); off += (size_t)M * 4;
    (void)ws_size; (void)n_in; (void)out_size;

    const int nTrTiles = (T >> 6) * (Dout >> 6);
    prep_kernel<<<M + T + nTrTiles, 256, 0, stream>>>(x, key, temp, val,
                                                      xb, kf, VT, rowsq, M, T, D, Dout);
    gemm_bt<0><<<dim3(M / 128, T / 128), 256, 0, stream>>>(xb, kf, sim, rowsq, M, T, D);
    gelu_kernel<<<M, 256, 0, stream>>>(sim, rowsq, T, sqrtf((float)T));
    gemm_bt<1><<<dim3(M / 128, Dout / 128), 256, 0, stream>>>(sim, VT, out, nullptr,
                                                              M, Dout, T);
}